// Round 1
// baseline (599.116 us; speedup 1.0000x reference)
//
#include <hip/hip_runtime.h>
#include <stdint.h>

typedef short bf16x8 __attribute__((ext_vector_type(8)));
typedef float f32x4 __attribute__((ext_vector_type(4)));
typedef unsigned short us4 __attribute__((ext_vector_type(4)));
typedef unsigned short us8 __attribute__((ext_vector_type(8)));

__device__ __forceinline__ unsigned short f2bf(float f) {
  union { float f; unsigned u; } v; v.f = f;
  unsigned r = v.u + 0x7fffu + ((v.u >> 16) & 1u);
  return (unsigned short)(r >> 16);
}

#define GL2LDS(g, l) __builtin_amdgcn_global_load_lds( \
    (const __attribute__((address_space(1))) void*)(g), \
    (__attribute__((address_space(3))) void*)(l), 16, 0, 0)

// ---------------- kernel 1: f32 -> bf16 conversion ----------------
__global__ __launch_bounds__(256) void convert_all(
    const float* __restrict__ q, const float* __restrict__ k, const float* __restrict__ v,
    const float* __restrict__ wq, const float* __restrict__ wk, const float* __restrict__ wv,
    const float* __restrict__ wo,
    unsigned short* __restrict__ qb, unsigned short* __restrict__ kb, unsigned short* __restrict__ vb,
    unsigned short* __restrict__ wqb, unsigned short* __restrict__ wkb, unsigned short* __restrict__ wvb,
    unsigned short* __restrict__ wob)
{
  const long NB = 8388608, NW = 1048576;
  long i = ((long)blockIdx.x * 256 + threadIdx.x) * 4;
  if (i >= 3*NB + 4*NW) return;
  const float* src; unsigned short* dst; long off;
  if (i < NB)              { src = q;  dst = qb;  off = i; }
  else if (i < 2*NB)       { src = k;  dst = kb;  off = i - NB; }
  else if (i < 3*NB)       { src = v;  dst = vb;  off = i - 2*NB; }
  else if (i < 3*NB+NW)    { src = wq; dst = wqb; off = i - 3*NB; }
  else if (i < 3*NB+2*NW)  { src = wk; dst = wkb; off = i - 3*NB - NW; }
  else if (i < 3*NB+3*NW)  { src = wv; dst = wvb; off = i - 3*NB - 2*NW; }
  else                     { src = wo; dst = wob; off = i - 3*NB - 3*NW; }
  float4 x = *(const float4*)(src + off);
  us4 o; o.x = f2bf(x.x); o.y = f2bf(x.y); o.z = f2bf(x.z); o.w = f2bf(x.w);
  *(us4*)(dst + off) = o;
}

// ---------------- kernel 2: QKV projection GEMM (bf16 MFMA, B^T form) ----------------
// C[m][n] = sum_k X[m][k] * W[n][k] + bias[n]; m in [0,8192), n in [0,1024), K=1024
// z=0 -> qh [h][b][l][dk], z=1 -> kh same, z=2 -> vt [h][b][dk][l]
__global__ __launch_bounds__(256, 2) void qkv_gemm(
    const unsigned short* __restrict__ qb, const unsigned short* __restrict__ kb,
    const unsigned short* __restrict__ vb,
    const unsigned short* __restrict__ wqb, const unsigned short* __restrict__ wkb,
    const unsigned short* __restrict__ wvb,
    const float* __restrict__ bq, const float* __restrict__ bk, const float* __restrict__ bv,
    unsigned short* __restrict__ qh, unsigned short* __restrict__ kh,
    unsigned short* __restrict__ vt)
{
  const int z = blockIdx.z;
  const unsigned short* X = (z == 0) ? qb : (z == 1) ? kb : vb;
  const unsigned short* W = (z == 0) ? wqb : (z == 1) ? wkb : wvb;
  const float* bias = (z == 0) ? bq : (z == 1) ? bk : bv;
  unsigned short* dqh = (z == 0) ? qh : kh;

  const int m0 = blockIdx.x * 128, n0 = blockIdx.y * 128;
  const int tid = threadIdx.x, lane = tid & 63, w = tid >> 6;
  const int wr = w >> 1, wc = w & 1;
  const int lg = lane >> 4, ll = lane & 15;

  __shared__ __align__(16) unsigned short As[128 * 32];
  __shared__ __align__(16) unsigned short Bs[128 * 32];

  f32x4 acc[4][4] = {};

  const char* gA = (const char*)X + ((size_t)(m0 + w*32 + (lane >> 2)) * 1024) * 2 + (lane & 3) * 16;
  const char* gB = (const char*)W + ((size_t)(n0 + w*32 + (lane >> 2)) * 1024) * 2 + (lane & 3) * 16;
  char* lA = (char*)As + w * 2048;
  char* lB = (char*)Bs + w * 2048;

  for (int k0 = 0; k0 < 1024; k0 += 32) {
    GL2LDS(gA,         lA);
    GL2LDS(gA + 32768, lA + 1024);
    GL2LDS(gB,         lB);
    GL2LDS(gB + 32768, lB + 1024);
    gA += 64; gB += 64;
    __syncthreads();
    bf16x8 a[4], b[4];
    const int kc = lg * 8;
#pragma unroll
    for (int f = 0; f < 4; ++f) a[f] = *(const bf16x8*)&As[(wr*64 + f*16 + ll)*32 + kc];
#pragma unroll
    for (int f = 0; f < 4; ++f) b[f] = *(const bf16x8*)&Bs[(wc*64 + f*16 + ll)*32 + kc];
#pragma unroll
    for (int fr = 0; fr < 4; ++fr)
#pragma unroll
      for (int fc = 0; fc < 4; ++fc)
        acc[fr][fc] = __builtin_amdgcn_mfma_f32_16x16x32_bf16(a[fr], b[fc], acc[fr][fc], 0, 0, 0);
    __syncthreads();
  }

#pragma unroll
  for (int fc = 0; fc < 4; ++fc) {
    const int n_g = n0 + wc*64 + fc*16 + ll;
    const float bias_n = bias[n_g];
    const int h = n_g >> 6, dkk = n_g & 63;
#pragma unroll
    for (int fr = 0; fr < 4; ++fr) {
      const int mrow = m0 + wr*64 + fr*16 + lg*4;
      if (z < 2) {
#pragma unroll
        for (int r = 0; r < 4; ++r) {
          const int m_g = mrow + r;
          const int b_ = m_g >> 11, l_ = m_g & 2047;
          dqh[((size_t)(h*4 + b_) * 2048 + l_) * 64 + dkk] = f2bf(acc[fr][fc][r] + bias_n);
        }
      } else {
        const int b_ = mrow >> 11, l_ = mrow & 2047;
        us4 pk;
#pragma unroll
        for (int r = 0; r < 4; ++r) pk[r] = f2bf(acc[fr][fc][r] + bias_n);
        *(us4*)&vt[((size_t)(h*4 + b_) * 64 + dkk) * 2048 + l_] = pk;
      }
    }
  }
}

// ---------------- kernel 3: attention ----------------
// grid (16 q-tiles, 64 h*B), 256 threads = 4 waves (2 q-split x 2 k-split)
#define SCL 0.18033688011112042f  /* log2(e)/sqrt(64) */

__global__ __launch_bounds__(256, 2) void attn_kernel(
    const unsigned short* __restrict__ qh, const unsigned short* __restrict__ kh,
    const unsigned short* __restrict__ vt, float* __restrict__ probs,
    unsigned short* __restrict__ attn_o)
{
  const int qt = blockIdx.x, hb = blockIdx.y;
  const int tid = threadIdx.x, lane = tid & 63, w = tid >> 6;
  const int wr = w >> 1, wc = w & 1;
  const int lg = lane >> 4, ll = lane & 15;

  __shared__ __align__(16) char smem[58880];
  unsigned short* Qs = (unsigned short*)smem;                     // [128][72]
  unsigned short* Ks = (unsigned short*)(smem + 18432);           // [64][72]
  unsigned short* Vs = (unsigned short*)(smem + 27648);           // [64][72] (V^T: [d][k])
  unsigned short* Ps = (unsigned short*)(smem + 36864) + w * 2560;// per-wave [64][40]
  float* rs   = (float*)(smem + 57344);                           // [2][128]
  float* invl = (float*)(smem + 58368);                           // [128]
  float* Ored = (float*)smem;                                     // reuse: [2][64][64] f32

  const size_t slab = (size_t)hb << 17;  // hb * 2048 * 64

  // stage Q tile [128][64] -> Qs (rows padded to 72 elems: 2-way-max bank conflicts)
#pragma unroll
  for (int it = 0; it < 4; ++it) {
    int e = (it*256 + tid) * 8;
    int row = e >> 6, col = e & 63;
    *(us8*)&Qs[row*72 + col] = *(const us8*)&qh[slab + (size_t)(qt*128 + row)*64 + col];
  }

  // ---- pass 1: row sums of exp(s/8) ----
  float rsum[4][4] = {};
  for (int kt = 0; kt < 32; ++kt) {
    __syncthreads();
#pragma unroll
    for (int it = 0; it < 2; ++it) {
      int e = (it*256 + tid) * 8;
      int row = e >> 6, col = e & 63;
      *(us8*)&Ks[row*72 + col] = *(const us8*)&kh[slab + (size_t)(kt*64 + row)*64 + col];
    }
    __syncthreads();
    f32x4 s[4][2] = {};
#pragma unroll
    for (int dh = 0; dh < 2; ++dh) {
      const int kc = dh*32 + lg*8;
      bf16x8 a[4], b[2];
#pragma unroll
      for (int f = 0; f < 4; ++f) a[f] = *(const bf16x8*)&Qs[(wr*64 + f*16 + ll)*72 + kc];
#pragma unroll
      for (int f = 0; f < 2; ++f) b[f] = *(const bf16x8*)&Ks[(wc*32 + f*16 + ll)*72 + kc];
#pragma unroll
      for (int fr = 0; fr < 4; ++fr)
#pragma unroll
        for (int fc = 0; fc < 2; ++fc)
          s[fr][fc] = __builtin_amdgcn_mfma_f32_16x16x32_bf16(a[fr], b[fc], s[fr][fc], 0, 0, 0);
    }
#pragma unroll
    for (int fr = 0; fr < 4; ++fr)
#pragma unroll
      for (int r = 0; r < 4; ++r)
        rsum[fr][r] += exp2f(s[fr][0][r]*SCL) + exp2f(s[fr][1][r]*SCL);
  }

  // reduce row sums across the 16 k-col lanes, publish, combine the 2 k-split waves
#pragma unroll
  for (int fr = 0; fr < 4; ++fr)
#pragma unroll
    for (int r = 0; r < 4; ++r) {
      float t = rsum[fr][r];
      t += __shfl_xor(t, 1); t += __shfl_xor(t, 2);
      t += __shfl_xor(t, 4); t += __shfl_xor(t, 8);
      rsum[fr][r] = t;
    }
  if (ll == 0) {
#pragma unroll
    for (int fr = 0; fr < 4; ++fr)
#pragma unroll
      for (int r = 0; r < 4; ++r)
        rs[wc*128 + wr*64 + fr*16 + lg*4 + r] = rsum[fr][r];
  }
  __syncthreads();
  if (tid < 128) invl[tid] = 1.0f / (rs[tid] + rs[128 + tid]);
  __syncthreads();
  float inv_r[4][4];
#pragma unroll
  for (int fr = 0; fr < 4; ++fr)
#pragma unroll
    for (int r = 0; r < 4; ++r)
      inv_r[fr][r] = invl[wr*64 + fr*16 + lg*4 + r];

  // ---- pass 2: recompute S, write P, accumulate O = P*V ----
  f32x4 o[4][4] = {};
  const size_t pb = ((size_t)hb << 22) + ((size_t)(qt*128 + wr*64) << 11);
  for (int kt = 0; kt < 32; ++kt) {
    __syncthreads();
#pragma unroll
    for (int it = 0; it < 2; ++it) {
      int e = (it*256 + tid) * 8;
      int row = e >> 6, col = e & 63;
      *(us8*)&Ks[row*72 + col] = *(const us8*)&kh[slab + (size_t)(kt*64 + row)*64 + col];
      *(us8*)&Vs[row*72 + col] = *(const us8*)&vt[slab + (size_t)row*2048 + kt*64 + col];
    }
    __syncthreads();
    f32x4 s[4][2] = {};
#pragma unroll
    for (int dh = 0; dh < 2; ++dh) {
      const int kc = dh*32 + lg*8;
      bf16x8 a[4], b[2];
#pragma unroll
      for (int f = 0; f < 4; ++f) a[f] = *(const bf16x8*)&Qs[(wr*64 + f*16 + ll)*72 + kc];
#pragma unroll
      for (int f = 0; f < 2; ++f) b[f] = *(const bf16x8*)&Ks[(wc*32 + f*16 + ll)*72 + kc];
#pragma unroll
      for (int fr = 0; fr < 4; ++fr)
#pragma unroll
        for (int fc = 0; fc < 2; ++fc)
          s[fr][fc] = __builtin_amdgcn_mfma_f32_16x16x32_bf16(a[fr], b[fc], s[fr][fc], 0, 0, 0);
    }
#pragma unroll
    for (int fr = 0; fr < 4; ++fr)
#pragma unroll
      for (int fc = 0; fc < 2; ++fc) {
        const int col_l = fc*16 + ll;
        const int kg = kt*64 + wc*32 + col_l;
#pragma unroll
        for (int r = 0; r < 4; ++r) {
          const int row_l = fr*16 + lg*4 + r;
          float p = exp2f(s[fr][fc][r]*SCL) * inv_r[fr][r];
          probs[pb + ((size_t)row_l << 11) + kg] = p;
          Ps[row_l*40 + col_l] = f2bf(p);
        }
      }
    // PV: O[64q][64d] += P[64q][32k] * V[32k][64d]  (V^T staged, B^T form)
    {
      const int kc = lg * 8;
      bf16x8 a[4], b[4];
#pragma unroll
      for (int f = 0; f < 4; ++f) a[f] = *(const bf16x8*)&Ps[(f*16 + ll)*40 + kc];
#pragma unroll
      for (int f = 0; f < 4; ++f) b[f] = *(const bf16x8*)&Vs[(f*16 + ll)*72 + wc*32 + kc];
#pragma unroll
      for (int fm = 0; fm < 4; ++fm)
#pragma unroll
        for (int fd = 0; fd < 4; ++fd)
          o[fm][fd] = __builtin_amdgcn_mfma_f32_16x16x32_bf16(a[fm], b[fd], o[fm][fd], 0, 0, 0);
    }
  }

  // ---- cross-wave (k-split) O reduction, write attn output [b][l][h*64+d] bf16 ----
  __syncthreads();
  if (wc == 1) {
#pragma unroll
    for (int fm = 0; fm < 4; ++fm)
#pragma unroll
      for (int fd = 0; fd < 4; ++fd)
#pragma unroll
        for (int r = 0; r < 4; ++r)
          Ored[wr*4096 + (fm*16 + lg*4 + r)*64 + fd*16 + ll] = o[fm][fd][r];
  }
  __syncthreads();
  if (wc == 0) {
    const int b_ = hb & 3, h = hb >> 2;
#pragma unroll
    for (int fm = 0; fm < 4; ++fm)
#pragma unroll
      for (int fd = 0; fd < 4; ++fd)
#pragma unroll
        for (int r = 0; r < 4; ++r) {
          const int qrow = fm*16 + lg*4 + r;
          const int d = fd*16 + ll;
          float val = o[fm][fd][r] + Ored[wr*4096 + qrow*64 + d];
          const int mg = b_*2048 + qt*128 + wr*64 + qrow;
          attn_o[(size_t)mg*1024 + h*64 + d] = f2bf(val);
        }
  }
}

// ---------------- kernel 4: output projection + bias + residual -> preLN (f32) ----------------
__global__ __launch_bounds__(256, 2) void outproj_gemm(
    const unsigned short* __restrict__ Ain, const unsigned short* __restrict__ Wob,
    const float* __restrict__ bo, const float* __restrict__ qres, float* __restrict__ preLN)
{
  const int m0 = blockIdx.x * 128, n0 = blockIdx.y * 128;
  const int tid = threadIdx.x, lane = tid & 63, w = tid >> 6;
  const int wr = w >> 1, wc = w & 1;
  const int lg = lane >> 4, ll = lane & 15;

  __shared__ __align__(16) unsigned short As[128 * 32];
  __shared__ __align__(16) unsigned short Bs[128 * 32];

  f32x4 acc[4][4] = {};

  const char* gA = (const char*)Ain + ((size_t)(m0 + w*32 + (lane >> 2)) * 1024) * 2 + (lane & 3) * 16;
  const char* gB = (const char*)Wob + ((size_t)(n0 + w*32 + (lane >> 2)) * 1024) * 2 + (lane & 3) * 16;
  char* lA = (char*)As + w * 2048;
  char* lB = (char*)Bs + w * 2048;

  for (int k0 = 0; k0 < 1024; k0 += 32) {
    GL2LDS(gA,         lA);
    GL2LDS(gA + 32768, lA + 1024);
    GL2LDS(gB,         lB);
    GL2LDS(gB + 32768, lB + 1024);
    gA += 64; gB += 64;
    __syncthreads();
    bf16x8 a[4], b[4];
    const int kc = lg * 8;
#pragma unroll
    for (int f = 0; f < 4; ++f) a[f] = *(const bf16x8*)&As[(wr*64 + f*16 + ll)*32 + kc];
#pragma unroll
    for (int f = 0; f < 4; ++f) b[f] = *(const bf16x8*)&Bs[(wc*64 + f*16 + ll)*32 + kc];
#pragma unroll
    for (int fr = 0; fr < 4; ++fr)
#pragma unroll
      for (int fc = 0; fc < 4; ++fc)
        acc[fr][fc] = __builtin_amdgcn_mfma_f32_16x16x32_bf16(a[fr], b[fc], acc[fr][fc], 0, 0, 0);
    __syncthreads();
  }

#pragma unroll
  for (int fc = 0; fc < 4; ++fc) {
    const int n_g = n0 + wc*64 + fc*16 + ll;
    const float bias_n = bo[n_g];
#pragma unroll
    for (int fr = 0; fr < 4; ++fr) {
#pragma unroll
      for (int r = 0; r < 4; ++r) {
        const int m_g = m0 + wr*64 + fr*16 + lg*4 + r;
        const size_t idx = (size_t)m_g * 1024 + n_g;
        preLN[idx] = acc[fr][fc][r] + bias_n + qres[idx];
      }
    }
  }
}

// ---------------- kernel 5: LayerNorm ----------------
__global__ __launch_bounds__(256) void ln_kernel(
    const float* __restrict__ x, const float* __restrict__ gamma,
    const float* __restrict__ beta, float* __restrict__ out)
{
  const int row = blockIdx.x, tid = threadIdx.x;
  const float4 xv = ((const float4*)(x + (size_t)row * 1024))[tid];
  float s = xv.x + xv.y + xv.z + xv.w;
  float ss = xv.x*xv.x + xv.y*xv.y + xv.z*xv.z + xv.w*xv.w;
#pragma unroll
  for (int m = 1; m < 64; m <<= 1) { s += __shfl_xor(s, m); ss += __shfl_xor(ss, m); }
  __shared__ float red[8];
  if ((tid & 63) == 0) { red[(tid >> 6)*2] = s; red[(tid >> 6)*2 + 1] = ss; }
  __syncthreads();
  s  = red[0] + red[2] + red[4] + red[6];
  ss = red[1] + red[3] + red[5] + red[7];
  const float mu = s * (1.0f/1024.0f);
  const float var = ss * (1.0f/1024.0f) - mu*mu;
  const float rstd = rsqrtf(var + 1e-5f);
  const float4 g  = ((const float4*)gamma)[tid];
  const float4 be = ((const float4*)beta)[tid];
  float4 y;
  y.x = (xv.x - mu)*rstd*g.x + be.x;
  y.y = (xv.y - mu)*rstd*g.y + be.y;
  y.z = (xv.z - mu)*rstd*g.z + be.z;
  y.w = (xv.w - mu)*rstd*g.w + be.w;
  ((float4*)(out + (size_t)row * 1024))[tid] = y;
}

// ---------------- launch ----------------
extern "C" void kernel_launch(void* const* d_in, const int* in_sizes, int n_in,
                              void* d_out, int out_size, void* d_ws, size_t ws_size,
                              hipStream_t stream) {
  const float* q     = (const float*)d_in[0];
  const float* k     = (const float*)d_in[1];
  const float* v     = (const float*)d_in[2];
  const float* Wq    = (const float*)d_in[3];
  const float* bq    = (const float*)d_in[4];
  const float* Wk    = (const float*)d_in[5];
  const float* bk    = (const float*)d_in[6];
  const float* Wv    = (const float*)d_in[7];
  const float* bv    = (const float*)d_in[8];
  const float* Wo    = (const float*)d_in[9];
  const float* bo    = (const float*)d_in[10];
  const float* gamma = (const float*)d_in[11];
  const float* beta  = (const float*)d_in[12];

  float* out   = (float*)d_out;
  float* probs = out + 8388608;       // attn_flat region: [64][2048][2048] f32

  char* ws = (char*)d_ws;
  unsigned short* qb  = (unsigned short*)(ws);
  unsigned short* kb  = (unsigned short*)(ws + 16777216);
  unsigned short* vb  = (unsigned short*)(ws + 33554432);
  unsigned short* wqb = (unsigned short*)(ws + 50331648);
  unsigned short* wkb = (unsigned short*)(ws + 52428800);
  unsigned short* wvb = (unsigned short*)(ws + 54525952);
  unsigned short* wob = (unsigned short*)(ws + 56623104);
  unsigned short* qh  = (unsigned short*)(ws + 58720256);  // [64 slabs][2048][64]
  unsigned short* kh  = (unsigned short*)(ws + 75497472);
  unsigned short* vt  = (unsigned short*)(ws + 92274688);  // [64 slabs][64][2048]
  float* preLN = (float*)(ws);                 // overlays qb+kb (dead by then)
  unsigned short* attn_o = vb;                 // overlays vb (dead by then)

  convert_all<<<28672, 256, 0, stream>>>(q, k, v, Wq, Wk, Wv, Wo,
                                         qb, kb, vb, wqb, wkb, wvb, wob);

  dim3 g1(64, 8, 3);
  qkv_gemm<<<g1, 256, 0, stream>>>(qb, kb, vb, wqb, wkb, wvb, bq, bk, bv, qh, kh, vt);

  dim3 g2(16, 64);
  attn_kernel<<<g2, 256, 0, stream>>>(qh, kh, vt, probs, attn_o);

  dim3 g3(64, 8);
  outproj_gemm<<<g3, 256, 0, stream>>>(attn_o, wob, bo, q, preLN);

  ln_kernel<<<8192, 256, 0, stream>>>(preLN, gamma, beta, out);
}

// Round 2
// 588.572 us; speedup vs baseline: 1.0179x; 1.0179x over previous
//
#include <hip/hip_runtime.h>
#include <stdint.h>

typedef short bf16x8 __attribute__((ext_vector_type(8)));
typedef float f32x4 __attribute__((ext_vector_type(4)));
typedef unsigned short us4 __attribute__((ext_vector_type(4)));
typedef unsigned short us8 __attribute__((ext_vector_type(8)));

__device__ __forceinline__ unsigned short f2bf(float f) {
  union { float f; unsigned u; } v; v.f = f;
  unsigned r = v.u + 0x7fffu + ((v.u >> 16) & 1u);
  return (unsigned short)(r >> 16);
}

#define GL2LDS(g, l) __builtin_amdgcn_global_load_lds( \
    (const __attribute__((address_space(1))) void*)(g), \
    (__attribute__((address_space(3))) void*)(l), 16, 0, 0)

// ---------------- kernel 1: f32 -> bf16 conversion ----------------
__global__ __launch_bounds__(256) void convert_all(
    const float* __restrict__ q, const float* __restrict__ k, const float* __restrict__ v,
    const float* __restrict__ wq, const float* __restrict__ wk, const float* __restrict__ wv,
    const float* __restrict__ wo,
    unsigned short* __restrict__ qb, unsigned short* __restrict__ kb, unsigned short* __restrict__ vb,
    unsigned short* __restrict__ wqb, unsigned short* __restrict__ wkb, unsigned short* __restrict__ wvb,
    unsigned short* __restrict__ wob)
{
  const long NB = 8388608, NW = 1048576;
  long i = ((long)blockIdx.x * 256 + threadIdx.x) * 4;
  if (i >= 3*NB + 4*NW) return;
  const float* src; unsigned short* dst; long off;
  if (i < NB)              { src = q;  dst = qb;  off = i; }
  else if (i < 2*NB)       { src = k;  dst = kb;  off = i - NB; }
  else if (i < 3*NB)       { src = v;  dst = vb;  off = i - 2*NB; }
  else if (i < 3*NB+NW)    { src = wq; dst = wqb; off = i - 3*NB; }
  else if (i < 3*NB+2*NW)  { src = wk; dst = wkb; off = i - 3*NB - NW; }
  else if (i < 3*NB+3*NW)  { src = wv; dst = wvb; off = i - 3*NB - 2*NW; }
  else                     { src = wo; dst = wob; off = i - 3*NB - 3*NW; }
  float4 x = *(const float4*)(src + off);
  us4 o; o.x = f2bf(x.x); o.y = f2bf(x.y); o.z = f2bf(x.z); o.w = f2bf(x.w);
  *(us4*)(dst + off) = o;
}

// ---------------- kernel 2: QKV projection GEMM (bf16 MFMA, B^T form) ----------------
__global__ __launch_bounds__(256, 2) void qkv_gemm(
    const unsigned short* __restrict__ qb, const unsigned short* __restrict__ kb,
    const unsigned short* __restrict__ vb,
    const unsigned short* __restrict__ wqb, const unsigned short* __restrict__ wkb,
    const unsigned short* __restrict__ wvb,
    const float* __restrict__ bq, const float* __restrict__ bk, const float* __restrict__ bv,
    unsigned short* __restrict__ qh, unsigned short* __restrict__ kh,
    unsigned short* __restrict__ vt)
{
  const int z = blockIdx.z;
  const unsigned short* X = (z == 0) ? qb : (z == 1) ? kb : vb;
  const unsigned short* W = (z == 0) ? wqb : (z == 1) ? wkb : wvb;
  const float* bias = (z == 0) ? bq : (z == 1) ? bk : bv;
  unsigned short* dqh = (z == 0) ? qh : kh;

  const int m0 = blockIdx.x * 128, n0 = blockIdx.y * 128;
  const int tid = threadIdx.x, lane = tid & 63, w = tid >> 6;
  const int wr = w >> 1, wc = w & 1;
  const int lg = lane >> 4, ll = lane & 15;

  __shared__ __align__(16) unsigned short As[128 * 32];
  __shared__ __align__(16) unsigned short Bs[128 * 32];

  f32x4 acc[4][4] = {};

  const char* gA = (const char*)X + ((size_t)(m0 + w*32 + (lane >> 2)) * 1024) * 2 + (lane & 3) * 16;
  const char* gB = (const char*)W + ((size_t)(n0 + w*32 + (lane >> 2)) * 1024) * 2 + (lane & 3) * 16;
  char* lA = (char*)As + w * 2048;
  char* lB = (char*)Bs + w * 2048;

  for (int k0 = 0; k0 < 1024; k0 += 32) {
    GL2LDS(gA,         lA);
    GL2LDS(gA + 32768, lA + 1024);
    GL2LDS(gB,         lB);
    GL2LDS(gB + 32768, lB + 1024);
    gA += 64; gB += 64;
    __syncthreads();
    bf16x8 a[4], b[4];
    const int kc = lg * 8;
#pragma unroll
    for (int f = 0; f < 4; ++f) a[f] = *(const bf16x8*)&As[(wr*64 + f*16 + ll)*32 + kc];
#pragma unroll
    for (int f = 0; f < 4; ++f) b[f] = *(const bf16x8*)&Bs[(wc*64 + f*16 + ll)*32 + kc];
#pragma unroll
    for (int fr = 0; fr < 4; ++fr)
#pragma unroll
      for (int fc = 0; fc < 4; ++fc)
        acc[fr][fc] = __builtin_amdgcn_mfma_f32_16x16x32_bf16(a[fr], b[fc], acc[fr][fc], 0, 0, 0);
    __syncthreads();
  }

#pragma unroll
  for (int fc = 0; fc < 4; ++fc) {
    const int n_g = n0 + wc*64 + fc*16 + ll;
    const float bias_n = bias[n_g];
    const int h = n_g >> 6, dkk = n_g & 63;
#pragma unroll
    for (int fr = 0; fr < 4; ++fr) {
      const int mrow = m0 + wr*64 + fr*16 + lg*4;
      if (z < 2) {
#pragma unroll
        for (int r = 0; r < 4; ++r) {
          const int m_g = mrow + r;
          const int b_ = m_g >> 11, l_ = m_g & 2047;
          dqh[((size_t)(h*4 + b_) * 2048 + l_) * 64 + dkk] = f2bf(acc[fr][fc][r] + bias_n);
        }
      } else {
        const int b_ = mrow >> 11, l_ = mrow & 2047;
        us4 pk;
#pragma unroll
        for (int r = 0; r < 4; ++r) pk[r] = f2bf(acc[fr][fc][r] + bias_n);
        *(us4*)&vt[((size_t)(h*4 + b_) * 64 + dkk) * 2048 + l_] = pk;
      }
    }
  }
}

// ---------------- kernel 3: attention (swapped QK^T, dbuf, reg-Q) ----------------
// 1024 blocks (decoded to qt, hb with XCD affinity), 256 threads = 4 waves
// wave = (wr q-half, wc k-half); S fragment: col(ll)=q, row(lg*4+r)=k
#define SCL 0.18033688011112042f  /* log2(e)/sqrt(64) */

__global__ __launch_bounds__(256, 2) void attn_kernel(
    const unsigned short* __restrict__ qh, const unsigned short* __restrict__ kh,
    const unsigned short* __restrict__ vt, float* __restrict__ probs,
    unsigned short* __restrict__ attn_o)
{
  // XCD-aware decode: all 16 q-tiles of one hb land on the same XCD (8 hb per XCD)
  const int bid = blockIdx.x;
  const int xcd = bid & 7;
  const int idx = bid >> 3;            // 0..127
  const int hb  = xcd * 8 + (idx & 7); // 0..63
  const int qt  = idx >> 3;            // 0..15

  const int tid = threadIdx.x, lane = tid & 63, w = tid >> 6;
  const int wr = w >> 1, wc = w & 1;
  const int lg = lane >> 4, ll = lane & 15;

  __shared__ __align__(16) char smem[58880];
  unsigned short* Ks = (unsigned short*)smem;                      // [2][64][72]
  unsigned short* Vs = (unsigned short*)(smem + 18432);            // [2][64][72]
  unsigned short* Ps = (unsigned short*)(smem + 36864) + w * 2560; // per-wave [64][40]
  float* rs   = (float*)(smem + 57344);                            // [2][128]
  float* invl = (float*)(smem + 58368);                            // [128]
  float* Ored = (float*)smem;                                      // epilogue overlay

  const size_t slab = (size_t)hb << 17;  // hb * 2048 * 64

  // Q fragments held in registers for both passes
  bf16x8 qf[4][2];
#pragma unroll
  for (int fq = 0; fq < 4; ++fq)
#pragma unroll
    for (int dh = 0; dh < 2; ++dh)
      qf[fq][dh] = *(const bf16x8*)&qh[slab + (size_t)(qt*128 + wr*64 + fq*16 + ll)*64 + dh*32 + lg*8];

  // staging geometry: thread covers row (it*32 + tid/8), col (tid%8)*8 of a 64x64 tile
  const int sr0 = tid >> 3, sc = (tid & 7) * 8;
  const unsigned short* Kg = kh + slab + (size_t)sr0 * 64 + sc;
  const unsigned short* Vg = vt + slab + (size_t)sr0 * 2048 + sc;

  // ---- pass 1: row sums of exp(s*scl) ----
  float rsum[4] = {0.f, 0.f, 0.f, 0.f};
  {
    us8 k0 = *(const us8*)(Kg);
    us8 k1 = *(const us8*)(Kg + 2048);
    *(us8*)&Ks[sr0*72 + sc] = k0;
    *(us8*)&Ks[(32 + sr0)*72 + sc] = k1;
  }
  __syncthreads();
  for (int kt = 0; kt < 32; ++kt) {
    const int cur = kt & 1;
    us8 k0, k1;
    if (kt < 31) {
      k0 = *(const us8*)(Kg + (size_t)(kt+1)*4096);
      k1 = *(const us8*)(Kg + (size_t)(kt+1)*4096 + 2048);
    }
    bf16x8 ka[2][2];
#pragma unroll
    for (int fk = 0; fk < 2; ++fk)
#pragma unroll
      for (int dh = 0; dh < 2; ++dh)
        ka[fk][dh] = *(const bf16x8*)&Ks[cur*4608 + (wc*32 + fk*16 + ll)*72 + dh*32 + lg*8];
    f32x4 s[2][4] = {};
#pragma unroll
    for (int dh = 0; dh < 2; ++dh)
#pragma unroll
      for (int fk = 0; fk < 2; ++fk)
#pragma unroll
        for (int fq = 0; fq < 4; ++fq)
          s[fk][fq] = __builtin_amdgcn_mfma_f32_16x16x32_bf16(ka[fk][dh], qf[fq][dh], s[fk][fq], 0, 0, 0);
#pragma unroll
    for (int fk = 0; fk < 2; ++fk)
#pragma unroll
      for (int fq = 0; fq < 4; ++fq)
#pragma unroll
        for (int r = 0; r < 4; ++r)
          rsum[fq] += exp2f(s[fk][fq][r] * SCL);
    if (kt < 31) {
      const int nb = cur ^ 1;
      *(us8*)&Ks[nb*4608 + sr0*72 + sc] = k0;
      *(us8*)&Ks[nb*4608 + (32 + sr0)*72 + sc] = k1;
    }
    __syncthreads();
  }

  // lane-local q rows: reduce across the 4 lg (k-quarter) groups, then across wc waves
#pragma unroll
  for (int fq = 0; fq < 4; ++fq) {
    float t = rsum[fq];
    t += __shfl_xor(t, 16);
    t += __shfl_xor(t, 32);
    rsum[fq] = t;
  }
  if (lg == 0) {
#pragma unroll
    for (int fq = 0; fq < 4; ++fq)
      rs[wc*128 + wr*64 + fq*16 + ll] = rsum[fq];
  }
  __syncthreads();
  if (tid < 128) invl[tid] = 1.0f / (rs[tid] + rs[128 + tid]);
  __syncthreads();
  float inv_r[4];
#pragma unroll
  for (int fq = 0; fq < 4; ++fq) inv_r[fq] = invl[wr*64 + fq*16 + ll];

  // ---- pass 2: recompute S, write P (f32x4 nontemporal), PV ----
  f32x4 o[4][4] = {};
  float* pbl = probs + ((size_t)hb << 22) + (size_t)(qt*128 + wr*64 + ll) * 2048 + wc*32 + lg*4;
  {
    us8 k0 = *(const us8*)(Kg);
    us8 k1 = *(const us8*)(Kg + 2048);
    us8 v0 = *(const us8*)(Vg);
    us8 v1 = *(const us8*)(Vg + 32*2048);
    *(us8*)&Ks[sr0*72 + sc] = k0;
    *(us8*)&Ks[(32 + sr0)*72 + sc] = k1;
    *(us8*)&Vs[sr0*72 + sc] = v0;
    *(us8*)&Vs[(32 + sr0)*72 + sc] = v1;
  }
  __syncthreads();
  for (int kt = 0; kt < 32; ++kt) {
    const int cur = kt & 1;
    us8 k0, k1, v0, v1;
    if (kt < 31) {
      k0 = *(const us8*)(Kg + (size_t)(kt+1)*4096);
      k1 = *(const us8*)(Kg + (size_t)(kt+1)*4096 + 2048);
      v0 = *(const us8*)(Vg + (kt+1)*64);
      v1 = *(const us8*)(Vg + 32*2048 + (kt+1)*64);
    }
    bf16x8 ka[2][2];
#pragma unroll
    for (int fk = 0; fk < 2; ++fk)
#pragma unroll
      for (int dh = 0; dh < 2; ++dh)
        ka[fk][dh] = *(const bf16x8*)&Ks[cur*4608 + (wc*32 + fk*16 + ll)*72 + dh*32 + lg*8];
    f32x4 s[2][4] = {};
#pragma unroll
    for (int dh = 0; dh < 2; ++dh)
#pragma unroll
      for (int fk = 0; fk < 2; ++fk)
#pragma unroll
        for (int fq = 0; fq < 4; ++fq)
          s[fk][fq] = __builtin_amdgcn_mfma_f32_16x16x32_bf16(ka[fk][dh], qf[fq][dh], s[fk][fq], 0, 0, 0);

    // softmax scale + P writes (f32x4 to probs, us4 bf16 to LDS)
#pragma unroll
    for (int fk = 0; fk < 2; ++fk)
#pragma unroll
      for (int fq = 0; fq < 4; ++fq) {
        f32x4 p4;
#pragma unroll
        for (int r = 0; r < 4; ++r)
          p4[r] = exp2f(s[fk][fq][r] * SCL) * inv_r[fq];
        __builtin_nontemporal_store(p4, (f32x4*)(pbl + (size_t)fq*32768 + kt*64 + fk*16));
        us4 pk;
#pragma unroll
        for (int r = 0; r < 4; ++r) pk[r] = f2bf(p4[r]);
        *(us4*)&Ps[(fq*16 + ll)*40 + fk*16 + lg*4] = pk;
      }

    // PV: O[64q][64d] += P[64q][32k] * V^T[64d][32k]
    {
      bf16x8 pa[4], vb[4];
#pragma unroll
      for (int f = 0; f < 4; ++f) pa[f] = *(const bf16x8*)&Ps[(f*16 + ll)*40 + lg*8];
#pragma unroll
      for (int f = 0; f < 4; ++f) vb[f] = *(const bf16x8*)&Vs[cur*4608 + (f*16 + ll)*72 + wc*32 + lg*8];
#pragma unroll
      for (int fm = 0; fm < 4; ++fm)
#pragma unroll
        for (int fd = 0; fd < 4; ++fd)
          o[fm][fd] = __builtin_amdgcn_mfma_f32_16x16x32_bf16(pa[fm], vb[fd], o[fm][fd], 0, 0, 0);
    }

    if (kt < 31) {
      const int nb = cur ^ 1;
      *(us8*)&Ks[nb*4608 + sr0*72 + sc] = k0;
      *(us8*)&Ks[nb*4608 + (32 + sr0)*72 + sc] = k1;
      *(us8*)&Vs[nb*4608 + sr0*72 + sc] = v0;
      *(us8*)&Vs[nb*4608 + (32 + sr0)*72 + sc] = v1;
    }
    __syncthreads();
  }

  // ---- cross-wave (k-split) O reduction, write attn output [b][l][h*64+d] bf16 ----
  if (wc == 1) {
#pragma unroll
    for (int fm = 0; fm < 4; ++fm)
#pragma unroll
      for (int fd = 0; fd < 4; ++fd)
#pragma unroll
        for (int r = 0; r < 4; ++r)
          Ored[wr*4096 + (fm*16 + lg*4 + r)*64 + fd*16 + ll] = o[fm][fd][r];
  }
  __syncthreads();
  if (wc == 0) {
    const int b_ = hb & 3, h = hb >> 2;
#pragma unroll
    for (int fm = 0; fm < 4; ++fm)
#pragma unroll
      for (int fd = 0; fd < 4; ++fd)
#pragma unroll
        for (int r = 0; r < 4; ++r) {
          const int qrow = fm*16 + lg*4 + r;
          const int d = fd*16 + ll;
          float val = o[fm][fd][r] + Ored[wr*4096 + qrow*64 + d];
          const int mg = b_*2048 + qt*128 + wr*64 + qrow;
          attn_o[(size_t)mg*1024 + h*64 + d] = f2bf(val);
        }
  }
}

// ---------------- kernel 4: output projection + bias + residual -> preLN (f32) ----------------
__global__ __launch_bounds__(256, 2) void outproj_gemm(
    const unsigned short* __restrict__ Ain, const unsigned short* __restrict__ Wob,
    const float* __restrict__ bo, const float* __restrict__ qres, float* __restrict__ preLN)
{
  const int m0 = blockIdx.x * 128, n0 = blockIdx.y * 128;
  const int tid = threadIdx.x, lane = tid & 63, w = tid >> 6;
  const int wr = w >> 1, wc = w & 1;
  const int lg = lane >> 4, ll = lane & 15;

  __shared__ __align__(16) unsigned short As[128 * 32];
  __shared__ __align__(16) unsigned short Bs[128 * 32];

  f32x4 acc[4][4] = {};

  const char* gA = (const char*)Ain + ((size_t)(m0 + w*32 + (lane >> 2)) * 1024) * 2 + (lane & 3) * 16;
  const char* gB = (const char*)Wob + ((size_t)(n0 + w*32 + (lane >> 2)) * 1024) * 2 + (lane & 3) * 16;
  char* lA = (char*)As + w * 2048;
  char* lB = (char*)Bs + w * 2048;

  for (int k0 = 0; k0 < 1024; k0 += 32) {
    GL2LDS(gA,         lA);
    GL2LDS(gA + 32768, lA + 1024);
    GL2LDS(gB,         lB);
    GL2LDS(gB + 32768, lB + 1024);
    gA += 64; gB += 64;
    __syncthreads();
    bf16x8 a[4], b[4];
    const int kc = lg * 8;
#pragma unroll
    for (int f = 0; f < 4; ++f) a[f] = *(const bf16x8*)&As[(wr*64 + f*16 + ll)*32 + kc];
#pragma unroll
    for (int f = 0; f < 4; ++f) b[f] = *(const bf16x8*)&Bs[(wc*64 + f*16 + ll)*32 + kc];
#pragma unroll
    for (int fr = 0; fr < 4; ++fr)
#pragma unroll
      for (int fc = 0; fc < 4; ++fc)
        acc[fr][fc] = __builtin_amdgcn_mfma_f32_16x16x32_bf16(a[fr], b[fc], acc[fr][fc], 0, 0, 0);
    __syncthreads();
  }

#pragma unroll
  for (int fc = 0; fc < 4; ++fc) {
    const int n_g = n0 + wc*64 + fc*16 + ll;
    const float bias_n = bo[n_g];
#pragma unroll
    for (int fr = 0; fr < 4; ++fr) {
#pragma unroll
      for (int r = 0; r < 4; ++r) {
        const int m_g = m0 + wr*64 + fr*16 + lg*4 + r;
        const size_t idx = (size_t)m_g * 1024 + n_g;
        preLN[idx] = acc[fr][fc][r] + bias_n + qres[idx];
      }
    }
  }
}

// ---------------- kernel 5: LayerNorm ----------------
__global__ __launch_bounds__(256) void ln_kernel(
    const float* __restrict__ x, const float* __restrict__ gamma,
    const float* __restrict__ beta, float* __restrict__ out)
{
  const int row = blockIdx.x, tid = threadIdx.x;
  const float4 xv = ((const float4*)(x + (size_t)row * 1024))[tid];
  float s = xv.x + xv.y + xv.z + xv.w;
  float ss = xv.x*xv.x + xv.y*xv.y + xv.z*xv.z + xv.w*xv.w;
#pragma unroll
  for (int m = 1; m < 64; m <<= 1) { s += __shfl_xor(s, m); ss += __shfl_xor(ss, m); }
  __shared__ float red[8];
  if ((tid & 63) == 0) { red[(tid >> 6)*2] = s; red[(tid >> 6)*2 + 1] = ss; }
  __syncthreads();
  s  = red[0] + red[2] + red[4] + red[6];
  ss = red[1] + red[3] + red[5] + red[7];
  const float mu = s * (1.0f/1024.0f);
  const float var = ss * (1.0f/1024.0f) - mu*mu;
  const float rstd = rsqrtf(var + 1e-5f);
  const float4 g  = ((const float4*)gamma)[tid];
  const float4 be = ((const float4*)beta)[tid];
  float4 y;
  y.x = (xv.x - mu)*rstd*g.x + be.x;
  y.y = (xv.y - mu)*rstd*g.y + be.y;
  y.z = (xv.z - mu)*rstd*g.z + be.z;
  y.w = (xv.w - mu)*rstd*g.w + be.w;
  ((float4*)(out + (size_t)row * 1024))[tid] = y;
}

// ---------------- launch ----------------
extern "C" void kernel_launch(void* const* d_in, const int* in_sizes, int n_in,
                              void* d_out, int out_size, void* d_ws, size_t ws_size,
                              hipStream_t stream) {
  const float* q     = (const float*)d_in[0];
  const float* k     = (const float*)d_in[1];
  const float* v     = (const float*)d_in[2];
  const float* Wq    = (const float*)d_in[3];
  const float* bq    = (const float*)d_in[4];
  const float* Wk    = (const float*)d_in[5];
  const float* bk    = (const float*)d_in[6];
  const float* Wv    = (const float*)d_in[7];
  const float* bv    = (const float*)d_in[8];
  const float* Wo    = (const float*)d_in[9];
  const float* bo    = (const float*)d_in[10];
  const float* gamma = (const float*)d_in[11];
  const float* beta  = (const float*)d_in[12];

  float* out   = (float*)d_out;
  float* probs = out + 8388608;       // attn_flat region: [64][2048][2048] f32

  char* ws = (char*)d_ws;
  unsigned short* qb  = (unsigned short*)(ws);
  unsigned short* kb  = (unsigned short*)(ws + 16777216);
  unsigned short* vb  = (unsigned short*)(ws + 33554432);
  unsigned short* wqb = (unsigned short*)(ws + 50331648);
  unsigned short* wkb = (unsigned short*)(ws + 52428800);
  unsigned short* wvb = (unsigned short*)(ws + 54525952);
  unsigned short* wob = (unsigned short*)(ws + 56623104);
  unsigned short* qh  = (unsigned short*)(ws + 58720256);  // [64 slabs][2048][64]
  unsigned short* kh  = (unsigned short*)(ws + 75497472);
  unsigned short* vt  = (unsigned short*)(ws + 92274688);  // [64 slabs][64][2048]
  float* preLN = (float*)(ws);                 // overlays qb+kb (dead by then)
  unsigned short* attn_o = vb;                 // overlays vb (dead by then)

  convert_all<<<28672, 256, 0, stream>>>(q, k, v, Wq, Wk, Wv, Wo,
                                         qb, kb, vb, wqb, wkb, wvb, wob);

  dim3 g1(64, 8, 3);
  qkv_gemm<<<g1, 256, 0, stream>>>(qb, kb, vb, wqb, wkb, wvb, bq, bk, bv, qh, kh, vt);

  attn_kernel<<<1024, 256, 0, stream>>>(qh, kh, vt, probs, attn_o);

  dim3 g3(64, 8);
  outproj_gemm<<<g3, 256, 0, stream>>>(attn_o, wob, bo, q, preLN);

  ln_kernel<<<8192, 256, 0, stream>>>(preLN, gamma, beta, out);
}

// Round 3
// 572.620 us; speedup vs baseline: 1.0463x; 1.0279x over previous
//
#include <hip/hip_runtime.h>
#include <stdint.h>

typedef short bf16x8 __attribute__((ext_vector_type(8)));
typedef float f32x4 __attribute__((ext_vector_type(4)));
typedef unsigned short us4 __attribute__((ext_vector_type(4)));
typedef unsigned short us8 __attribute__((ext_vector_type(8)));

__device__ __forceinline__ unsigned short f2bf(float f) {
  union { float f; unsigned u; } v; v.f = f;
  unsigned r = v.u + 0x7fffu + ((v.u >> 16) & 1u);
  return (unsigned short)(r >> 16);
}

#define GL2LDS(g, l) __builtin_amdgcn_global_load_lds( \
    (const __attribute__((address_space(1))) void*)(g), \
    (__attribute__((address_space(3))) void*)(l), 16, 0, 0)

// ---------------- kernel 1: f32 -> bf16 conversion ----------------
__global__ __launch_bounds__(256) void convert_all(
    const float* __restrict__ q, const float* __restrict__ k, const float* __restrict__ v,
    const float* __restrict__ wq, const float* __restrict__ wk, const float* __restrict__ wv,
    const float* __restrict__ wo,
    unsigned short* __restrict__ qb, unsigned short* __restrict__ kb, unsigned short* __restrict__ vb,
    unsigned short* __restrict__ wqb, unsigned short* __restrict__ wkb, unsigned short* __restrict__ wvb,
    unsigned short* __restrict__ wob)
{
  const long NB = 8388608, NW = 1048576;
  long i = ((long)blockIdx.x * 256 + threadIdx.x) * 4;
  if (i >= 3*NB + 4*NW) return;
  const float* src; unsigned short* dst; long off;
  if (i < NB)              { src = q;  dst = qb;  off = i; }
  else if (i < 2*NB)       { src = k;  dst = kb;  off = i - NB; }
  else if (i < 3*NB)       { src = v;  dst = vb;  off = i - 2*NB; }
  else if (i < 3*NB+NW)    { src = wq; dst = wqb; off = i - 3*NB; }
  else if (i < 3*NB+2*NW)  { src = wk; dst = wkb; off = i - 3*NB - NW; }
  else if (i < 3*NB+3*NW)  { src = wv; dst = wvb; off = i - 3*NB - 2*NW; }
  else                     { src = wo; dst = wob; off = i - 3*NB - 3*NW; }
  float4 x = *(const float4*)(src + off);
  us4 o; o.x = f2bf(x.x); o.y = f2bf(x.y); o.z = f2bf(x.z); o.w = f2bf(x.w);
  *(us4*)(dst + off) = o;
}

// ---------------- kernel 2: QKV projection GEMM (bf16 MFMA, B^T form) ----------------
__global__ __launch_bounds__(256, 2) void qkv_gemm(
    const unsigned short* __restrict__ qb, const unsigned short* __restrict__ kb,
    const unsigned short* __restrict__ vb,
    const unsigned short* __restrict__ wqb, const unsigned short* __restrict__ wkb,
    const unsigned short* __restrict__ wvb,
    const float* __restrict__ bq, const float* __restrict__ bk, const float* __restrict__ bv,
    unsigned short* __restrict__ qh, unsigned short* __restrict__ kh,
    unsigned short* __restrict__ vt)
{
  const int z = blockIdx.z;
  const unsigned short* X = (z == 0) ? qb : (z == 1) ? kb : vb;
  const unsigned short* W = (z == 0) ? wqb : (z == 1) ? wkb : wvb;
  const float* bias = (z == 0) ? bq : (z == 1) ? bk : bv;
  unsigned short* dqh = (z == 0) ? qh : kh;

  const int m0 = blockIdx.x * 128, n0 = blockIdx.y * 128;
  const int tid = threadIdx.x, lane = tid & 63, w = tid >> 6;
  const int wr = w >> 1, wc = w & 1;
  const int lg = lane >> 4, ll = lane & 15;

  __shared__ __align__(16) unsigned short As[128 * 32];
  __shared__ __align__(16) unsigned short Bs[128 * 32];

  f32x4 acc[4][4] = {};

  const char* gA = (const char*)X + ((size_t)(m0 + w*32 + (lane >> 2)) * 1024) * 2 + (lane & 3) * 16;
  const char* gB = (const char*)W + ((size_t)(n0 + w*32 + (lane >> 2)) * 1024) * 2 + (lane & 3) * 16;
  char* lA = (char*)As + w * 2048;
  char* lB = (char*)Bs + w * 2048;

  for (int k0 = 0; k0 < 1024; k0 += 32) {
    GL2LDS(gA,         lA);
    GL2LDS(gA + 32768, lA + 1024);
    GL2LDS(gB,         lB);
    GL2LDS(gB + 32768, lB + 1024);
    gA += 64; gB += 64;
    __syncthreads();
    bf16x8 a[4], b[4];
    const int kc = lg * 8;
#pragma unroll
    for (int f = 0; f < 4; ++f) a[f] = *(const bf16x8*)&As[(wr*64 + f*16 + ll)*32 + kc];
#pragma unroll
    for (int f = 0; f < 4; ++f) b[f] = *(const bf16x8*)&Bs[(wc*64 + f*16 + ll)*32 + kc];
#pragma unroll
    for (int fr = 0; fr < 4; ++fr)
#pragma unroll
      for (int fc = 0; fc < 4; ++fc)
        acc[fr][fc] = __builtin_amdgcn_mfma_f32_16x16x32_bf16(a[fr], b[fc], acc[fr][fc], 0, 0, 0);
    __syncthreads();
  }

#pragma unroll
  for (int fc = 0; fc < 4; ++fc) {
    const int n_g = n0 + wc*64 + fc*16 + ll;
    const float bias_n = bias[n_g];
    const int h = n_g >> 6, dkk = n_g & 63;
#pragma unroll
    for (int fr = 0; fr < 4; ++fr) {
      const int mrow = m0 + wr*64 + fr*16 + lg*4;
      if (z < 2) {
#pragma unroll
        for (int r = 0; r < 4; ++r) {
          const int m_g = mrow + r;
          const int b_ = m_g >> 11, l_ = m_g & 2047;
          dqh[((size_t)(h*4 + b_) * 2048 + l_) * 64 + dkk] = f2bf(acc[fr][fc][r] + bias_n);
        }
      } else {
        const int b_ = mrow >> 11, l_ = mrow & 2047;
        us4 pk;
#pragma unroll
        for (int r = 0; r < 4; ++r) pk[r] = f2bf(acc[fr][fc][r] + bias_n);
        *(us4*)&vt[((size_t)(h*4 + b_) * 64 + dkk) * 2048 + l_] = pk;
      }
    }
  }
}

// ---------------- kernel 3: attention v3 (barrier-free, K/V direct-to-reg) ----------------
// 1024 blocks (XCD-affine decode), 256 threads = 4 waves (wr q-half, wc k-half)
// Swapped QK^T: S fragment col(ll)=q, row(lg*4+r)=k
#define SCL 0.18033688011112042f  /* log2(e)/sqrt(64) */

__global__ __launch_bounds__(256, 2) void attn_kernel(
    const unsigned short* __restrict__ qh, const unsigned short* __restrict__ kh,
    const unsigned short* __restrict__ vt, float* __restrict__ probs,
    unsigned short* __restrict__ attn_o)
{
  const int bid = blockIdx.x;
  const int xcd = bid & 7;
  const int idx = bid >> 3;
  const int hb  = xcd * 8 + (idx & 7);
  const int qt  = idx >> 3;

  const int tid = threadIdx.x, lane = tid & 63, w = tid >> 6;
  const int wr = w >> 1, wc = w & 1;
  const int lg = lane >> 4, ll = lane & 15;

  __shared__ __align__(16) char smem[33792];
  unsigned short* Ps = (unsigned short*)(smem) + w * 2560;  // per-wave [64][40]
  float* rs   = (float*)(smem + 20480);                     // [2][128]
  float* invl = (float*)(smem + 21504);                     // [128]
  float* Ored = (float*)smem;                               // epilogue overlay [2][64][64]

  const size_t slab = (size_t)hb << 17;  // hb * 2048 * 64

  // Q fragments in registers
  bf16x8 qf[4][2];
#pragma unroll
  for (int fq = 0; fq < 4; ++fq)
#pragma unroll
    for (int dh = 0; dh < 2; ++dh)
      qf[fq][dh] = *(const bf16x8*)&qh[slab + (size_t)(qt*128 + wr*64 + fq*16 + ll)*64 + dh*32 + lg*8];

  // per-lane K/V fragment bases (direct global reads, L2-resident slab)
  const unsigned short* Kf = kh + slab + (size_t)(wc*32 + ll)*64 + lg*8;   // + kt*4096 + fk*1024 + dh*32
  const unsigned short* Vf = vt + slab + (size_t)ll*2048 + wc*32 + lg*8;   // + f*32768 + kt*64

  // ---- pass 1: row sums of exp(s*scl); no LDS, no barriers ----
  float rsum[4] = {0.f, 0.f, 0.f, 0.f};
  for (int kt = 0; kt < 32; ++kt) {
    bf16x8 ka[2][2];
#pragma unroll
    for (int fk = 0; fk < 2; ++fk)
#pragma unroll
      for (int dh = 0; dh < 2; ++dh)
        ka[fk][dh] = *(const bf16x8*)(Kf + kt*4096 + fk*1024 + dh*32);
    f32x4 s[2][4] = {};
    __builtin_amdgcn_s_setprio(1);
#pragma unroll
    for (int dh = 0; dh < 2; ++dh)
#pragma unroll
      for (int fk = 0; fk < 2; ++fk)
#pragma unroll
        for (int fq = 0; fq < 4; ++fq)
          s[fk][fq] = __builtin_amdgcn_mfma_f32_16x16x32_bf16(ka[fk][dh], qf[fq][dh], s[fk][fq], 0, 0, 0);
    __builtin_amdgcn_s_setprio(0);
#pragma unroll
    for (int fk = 0; fk < 2; ++fk)
#pragma unroll
      for (int fq = 0; fq < 4; ++fq)
#pragma unroll
        for (int r = 0; r < 4; ++r)
          rsum[fq] += exp2f(s[fk][fq][r] * SCL);
  }

  // reduce across lg groups (k-quarters) and wc waves
#pragma unroll
  for (int fq = 0; fq < 4; ++fq) {
    float t = rsum[fq];
    t += __shfl_xor(t, 16);
    t += __shfl_xor(t, 32);
    rsum[fq] = t;
  }
  if (lg == 0) {
#pragma unroll
    for (int fq = 0; fq < 4; ++fq)
      rs[wc*128 + wr*64 + fq*16 + ll] = rsum[fq];
  }
  __syncthreads();
  if (tid < 128) invl[tid] = 1.0f / (rs[tid] + rs[128 + tid]);
  __syncthreads();
  float inv_r[4];
#pragma unroll
  for (int fq = 0; fq < 4; ++fq) inv_r[fq] = invl[wr*64 + fq*16 + ll];

  // ---- pass 2: recompute S, write P (f32x4 nontemporal), PV; barrier-free ----
  f32x4 o[4][4] = {};
  float* pbl = probs + ((size_t)hb << 22) + (size_t)(qt*128 + wr*64 + ll) * 2048 + wc*32 + lg*4;
  for (int kt = 0; kt < 32; ++kt) {
    bf16x8 ka[2][2], vb[4];
#pragma unroll
    for (int fk = 0; fk < 2; ++fk)
#pragma unroll
      for (int dh = 0; dh < 2; ++dh)
        ka[fk][dh] = *(const bf16x8*)(Kf + kt*4096 + fk*1024 + dh*32);
#pragma unroll
    for (int f = 0; f < 4; ++f)
      vb[f] = *(const bf16x8*)(Vf + f*32768 + kt*64);

    f32x4 s[2][4] = {};
    __builtin_amdgcn_s_setprio(1);
#pragma unroll
    for (int dh = 0; dh < 2; ++dh)
#pragma unroll
      for (int fk = 0; fk < 2; ++fk)
#pragma unroll
        for (int fq = 0; fq < 4; ++fq)
          s[fk][fq] = __builtin_amdgcn_mfma_f32_16x16x32_bf16(ka[fk][dh], qf[fq][dh], s[fk][fq], 0, 0, 0);
    __builtin_amdgcn_s_setprio(0);

    // softmax scale + P writes (f32x4 nontemporal to probs, us4 bf16 to per-wave LDS)
#pragma unroll
    for (int fk = 0; fk < 2; ++fk)
#pragma unroll
      for (int fq = 0; fq < 4; ++fq) {
        f32x4 p4;
#pragma unroll
        for (int r = 0; r < 4; ++r)
          p4[r] = exp2f(s[fk][fq][r] * SCL) * inv_r[fq];
        __builtin_nontemporal_store(p4, (f32x4*)(pbl + (size_t)fq*32768 + kt*64 + fk*16));
        us4 pk;
#pragma unroll
        for (int r = 0; r < 4; ++r) pk[r] = f2bf(p4[r]);
        *(us4*)&Ps[(fq*16 + ll)*40 + fk*16 + lg*4] = pk;
      }

    // PV: O[64q][64d] += P[64q][32k] * V^T[64d][32k]  (per-wave LDS exchange only)
    {
      bf16x8 pa[4];
#pragma unroll
      for (int f = 0; f < 4; ++f) pa[f] = *(const bf16x8*)&Ps[(f*16 + ll)*40 + lg*8];
      __builtin_amdgcn_s_setprio(1);
#pragma unroll
      for (int fm = 0; fm < 4; ++fm)
#pragma unroll
        for (int fd = 0; fd < 4; ++fd)
          o[fm][fd] = __builtin_amdgcn_mfma_f32_16x16x32_bf16(pa[fm], vb[fd], o[fm][fd], 0, 0, 0);
      __builtin_amdgcn_s_setprio(0);
    }
  }

  // ---- cross-wave (k-split) O reduction, write attn output [b][l][h*64+d] bf16 ----
  __syncthreads();
  if (wc == 1) {
#pragma unroll
    for (int fm = 0; fm < 4; ++fm)
#pragma unroll
      for (int fd = 0; fd < 4; ++fd)
#pragma unroll
        for (int r = 0; r < 4; ++r)
          Ored[wr*4096 + (fm*16 + lg*4 + r)*64 + fd*16 + ll] = o[fm][fd][r];
  }
  __syncthreads();
  if (wc == 0) {
    const int b_ = hb & 3, h = hb >> 2;
#pragma unroll
    for (int fm = 0; fm < 4; ++fm)
#pragma unroll
      for (int fd = 0; fd < 4; ++fd)
#pragma unroll
        for (int r = 0; r < 4; ++r) {
          const int qrow = fm*16 + lg*4 + r;
          const int d = fd*16 + ll;
          float val = o[fm][fd][r] + Ored[wr*4096 + qrow*64 + d];
          const int mg = b_*2048 + qt*128 + wr*64 + qrow;
          attn_o[(size_t)mg*1024 + h*64 + d] = f2bf(val);
        }
  }
}

// ---------------- kernel 4: output projection + bias + residual -> preLN (f32) ----------------
__global__ __launch_bounds__(256, 2) void outproj_gemm(
    const unsigned short* __restrict__ Ain, const unsigned short* __restrict__ Wob,
    const float* __restrict__ bo, const float* __restrict__ qres, float* __restrict__ preLN)
{
  const int m0 = blockIdx.x * 128, n0 = blockIdx.y * 128;
  const int tid = threadIdx.x, lane = tid & 63, w = tid >> 6;
  const int wr = w >> 1, wc = w & 1;
  const int lg = lane >> 4, ll = lane & 15;

  __shared__ __align__(16) unsigned short As[128 * 32];
  __shared__ __align__(16) unsigned short Bs[128 * 32];

  f32x4 acc[4][4] = {};

  const char* gA = (const char*)Ain + ((size_t)(m0 + w*32 + (lane >> 2)) * 1024) * 2 + (lane & 3) * 16;
  const char* gB = (const char*)Wob + ((size_t)(n0 + w*32 + (lane >> 2)) * 1024) * 2 + (lane & 3) * 16;
  char* lA = (char*)As + w * 2048;
  char* lB = (char*)Bs + w * 2048;

  for (int k0 = 0; k0 < 1024; k0 += 32) {
    GL2LDS(gA,         lA);
    GL2LDS(gA + 32768, lA + 1024);
    GL2LDS(gB,         lB);
    GL2LDS(gB + 32768, lB + 1024);
    gA += 64; gB += 64;
    __syncthreads();
    bf16x8 a[4], b[4];
    const int kc = lg * 8;
#pragma unroll
    for (int f = 0; f < 4; ++f) a[f] = *(const bf16x8*)&As[(wr*64 + f*16 + ll)*32 + kc];
#pragma unroll
    for (int f = 0; f < 4; ++f) b[f] = *(const bf16x8*)&Bs[(wc*64 + f*16 + ll)*32 + kc];
#pragma unroll
    for (int fr = 0; fr < 4; ++fr)
#pragma unroll
      for (int fc = 0; fc < 4; ++fc)
        acc[fr][fc] = __builtin_amdgcn_mfma_f32_16x16x32_bf16(a[fr], b[fc], acc[fr][fc], 0, 0, 0);
    __syncthreads();
  }

#pragma unroll
  for (int fc = 0; fc < 4; ++fc) {
    const int n_g = n0 + wc*64 + fc*16 + ll;
    const float bias_n = bo[n_g];
#pragma unroll
    for (int fr = 0; fr < 4; ++fr) {
#pragma unroll
      for (int r = 0; r < 4; ++r) {
        const int m_g = m0 + wr*64 + fr*16 + lg*4 + r;
        const size_t idx = (size_t)m_g * 1024 + n_g;
        preLN[idx] = acc[fr][fc][r] + bias_n + qres[idx];
      }
    }
  }
}

// ---------------- kernel 5: LayerNorm ----------------
__global__ __launch_bounds__(256) void ln_kernel(
    const float* __restrict__ x, const float* __restrict__ gamma,
    const float* __restrict__ beta, float* __restrict__ out)
{
  const int row = blockIdx.x, tid = threadIdx.x;
  const float4 xv = ((const float4*)(x + (size_t)row * 1024))[tid];
  float s = xv.x + xv.y + xv.z + xv.w;
  float ss = xv.x*xv.x + xv.y*xv.y + xv.z*xv.z + xv.w*xv.w;
#pragma unroll
  for (int m = 1; m < 64; m <<= 1) { s += __shfl_xor(s, m); ss += __shfl_xor(ss, m); }
  __shared__ float red[8];
  if ((tid & 63) == 0) { red[(tid >> 6)*2] = s; red[(tid >> 6)*2 + 1] = ss; }
  __syncthreads();
  s  = red[0] + red[2] + red[4] + red[6];
  ss = red[1] + red[3] + red[5] + red[7];
  const float mu = s * (1.0f/1024.0f);
  const float var = ss * (1.0f/1024.0f) - mu*mu;
  const float rstd = rsqrtf(var + 1e-5f);
  const float4 g  = ((const float4*)gamma)[tid];
  const float4 be = ((const float4*)beta)[tid];
  float4 y;
  y.x = (xv.x - mu)*rstd*g.x + be.x;
  y.y = (xv.y - mu)*rstd*g.y + be.y;
  y.z = (xv.z - mu)*rstd*g.z + be.z;
  y.w = (xv.w - mu)*rstd*g.w + be.w;
  ((float4*)(out + (size_t)row * 1024))[tid] = y;
}

// ---------------- launch ----------------
extern "C" void kernel_launch(void* const* d_in, const int* in_sizes, int n_in,
                              void* d_out, int out_size, void* d_ws, size_t ws_size,
                              hipStream_t stream) {
  const float* q     = (const float*)d_in[0];
  const float* k     = (const float*)d_in[1];
  const float* v     = (const float*)d_in[2];
  const float* Wq    = (const float*)d_in[3];
  const float* bq    = (const float*)d_in[4];
  const float* Wk    = (const float*)d_in[5];
  const float* bk    = (const float*)d_in[6];
  const float* Wv    = (const float*)d_in[7];
  const float* bv    = (const float*)d_in[8];
  const float* Wo    = (const float*)d_in[9];
  const float* bo    = (const float*)d_in[10];
  const float* gamma = (const float*)d_in[11];
  const float* beta  = (const float*)d_in[12];

  float* out   = (float*)d_out;
  float* probs = out + 8388608;       // attn_flat region: [64][2048][2048] f32

  char* ws = (char*)d_ws;
  unsigned short* qb  = (unsigned short*)(ws);
  unsigned short* kb  = (unsigned short*)(ws + 16777216);
  unsigned short* vb  = (unsigned short*)(ws + 33554432);
  unsigned short* wqb = (unsigned short*)(ws + 50331648);
  unsigned short* wkb = (unsigned short*)(ws + 52428800);
  unsigned short* wvb = (unsigned short*)(ws + 54525952);
  unsigned short* wob = (unsigned short*)(ws + 56623104);
  unsigned short* qh  = (unsigned short*)(ws + 58720256);  // [64 slabs][2048][64]
  unsigned short* kh  = (unsigned short*)(ws + 75497472);
  unsigned short* vt  = (unsigned short*)(ws + 92274688);  // [64 slabs][64][2048]
  float* preLN = (float*)(ws);                 // overlays qb+kb (dead by then)
  unsigned short* attn_o = vb;                 // overlays vb (dead by then)

  convert_all<<<28672, 256, 0, stream>>>(q, k, v, Wq, Wk, Wv, Wo,
                                         qb, kb, vb, wqb, wkb, wvb, wob);

  dim3 g1(64, 8, 3);
  qkv_gemm<<<g1, 256, 0, stream>>>(qb, kb, vb, wqb, wkb, wvb, bq, bk, bv, qh, kh, vt);

  attn_kernel<<<1024, 256, 0, stream>>>(qh, kh, vt, probs, attn_o);

  dim3 g3(64, 8);
  outproj_gemm<<<g3, 256, 0, stream>>>(attn_o, wob, bo, q, preLN);

  ln_kernel<<<8192, 256, 0, stream>>>(preLN, gamma, beta, out);
}